// Round 1
// baseline (567.142 us; speedup 1.0000x reference)
//
#include <hip/hip_runtime.h>
#include <hip/hip_bf16.h>

#define CH 64          // IN_C = HID_C = OUT_C = 64
#define BSH 9          // bucket shift: 512 nodes/bucket
#define CHUNK 16384    // edges per block in hist/scatter passes (1024 thr x 16)
#define MAXB 10240     // LDS col buffer (edges/bucket ~8163 +- 90)
// pairs packing: src < 2^17 (N=100000 <= 131072), dstLocal < 2^9 -> 26 bits

// ---------- CSR build: two-level counting sort, all atomics in LDS ----------

__global__ __launch_bounds__(1024)
void coarse_hist_kernel(const int* __restrict__ dst, int* __restrict__ blockHist,
                        int E, int nb) {
    __shared__ int h[256];
    int t = threadIdx.x;
    for (int i = t; i < nb; i += 1024) h[i] = 0;
    __syncthreads();
    int base = blockIdx.x * CHUNK + t * 16;
#pragma unroll
    for (int j = 0; j < 16; j += 4) {
        int e = base + j;
        if (e + 3 < E) {
            int4 d = *(const int4*)(dst + e);
            atomicAdd(&h[d.x >> BSH], 1);
            atomicAdd(&h[d.y >> BSH], 1);
            atomicAdd(&h[d.z >> BSH], 1);
            atomicAdd(&h[d.w >> BSH], 1);
        } else {
            for (int k = e; k < E && k < e + 4; ++k) atomicAdd(&h[dst[k] >> BSH], 1);
        }
    }
    __syncthreads();
    for (int i = t; i < nb; i += 1024) blockHist[blockIdx.x * nb + i] = h[i];
}

__global__ __launch_bounds__(256)
void scan_hist_kernel(int* __restrict__ blockHist, int* __restrict__ bucketStart,
                      int nblk, int nb, float* __restrict__ so) {
    __shared__ int tots[256];
    __shared__ int scn[257];
    int t = threadIdx.x;
    if (t == 0) { so[2] = 0.f; so[3] = 0.f; }   // zero LN accumulators each run
    if (t < nb) {
        int s = 0;
        for (int blk = 0; blk < nblk; ++blk) s += blockHist[blk * nb + t];
        tots[t] = s;
    }
    __syncthreads();
    if (t == 0) {
        int r = 0;
        for (int b = 0; b < nb; ++b) { scn[b] = r; r += tots[b]; }
        scn[nb] = r;
    }
    __syncthreads();
    if (t < nb) {
        int r = scn[t];
        for (int blk = 0; blk < nblk; ++blk) {
            int v = blockHist[blk * nb + t];
            blockHist[blk * nb + t] = r;   // in-place: now absolute base
            r += v;
        }
    }
    if (t <= nb) bucketStart[t] = scn[t];
}

// pairs entry: (dstLocal << 17) | src  (one 4B word/edge — halves the
// random-region write traffic vs int2)
__global__ __launch_bounds__(1024)
void scatter_pairs_kernel(const int* __restrict__ src, const int* __restrict__ dst,
                          const int* __restrict__ blockBase, unsigned* __restrict__ pairs,
                          int E, int nb) {
    __shared__ int cur[256];
    int t = threadIdx.x;
    for (int i = t; i < nb; i += 1024) cur[i] = blockBase[blockIdx.x * nb + i];
    __syncthreads();
    int base = blockIdx.x * CHUNK + t * 16;
#pragma unroll
    for (int j = 0; j < 16; j += 4) {
        int e = base + j;
        if (e + 3 < E) {
            int4 d = *(const int4*)(dst + e);
            int4 s = *(const int4*)(src + e);
            int p0 = atomicAdd(&cur[d.x >> BSH], 1);
            pairs[p0] = ((unsigned)(d.x & 511) << 17) | (unsigned)s.x;
            int p1 = atomicAdd(&cur[d.y >> BSH], 1);
            pairs[p1] = ((unsigned)(d.y & 511) << 17) | (unsigned)s.y;
            int p2 = atomicAdd(&cur[d.z >> BSH], 1);
            pairs[p2] = ((unsigned)(d.z & 511) << 17) | (unsigned)s.z;
            int p3 = atomicAdd(&cur[d.w >> BSH], 1);
            pairs[p3] = ((unsigned)(d.w & 511) << 17) | (unsigned)s.w;
        } else {
            for (int k = e; k < E && k < e + 4; ++k) {
                int d = dst[k];
                int p = atomicAdd(&cur[d >> BSH], 1);
                pairs[p] = ((unsigned)(d & 511) << 17) | (unsigned)src[k];
            }
        }
    }
}

__global__ __launch_bounds__(1024)
void bucket_csr_kernel(const unsigned* __restrict__ pairs, const int* __restrict__ bucketStart,
                       int* __restrict__ col, int* __restrict__ rs, float* __restrict__ dis,
                       int N, int nb) {
    __shared__ int hist[512];
    __shared__ int offs[512];
    __shared__ int cursor[512];
    __shared__ int lcol[MAXB];
    int b = blockIdx.x;
    int t = threadIdx.x;
    int n0 = b << BSH;
    int nn = min(512, N - n0);
    int start = bucketStart[b];
    int endp = bucketStart[b + 1];
    int cnt = endp - start;
    bool big = cnt > MAXB;  // safety fallback: direct (uncoalesced) col writes
    for (int i = t; i < nn; i += 1024) hist[i] = 0;
    __syncthreads();
    for (int i = start + t; i < endp; i += 1024) {
        unsigned p = pairs[i];
        atomicAdd(&hist[p >> 17], 1);
    }
    __syncthreads();
    if (t < 512) offs[t] = (t < nn) ? hist[t] : 0;
    __syncthreads();
    for (int off = 1; off < 512; off <<= 1) {
        int a = (t < 512 && t >= off) ? offs[t - off] : 0;
        __syncthreads();
        if (t < 512) offs[t] += a;
        __syncthreads();
    }
    if (t < nn) {
        int excl = offs[t] - hist[t];          // exclusive scan value
        rs[n0 + t] = start + excl;
        dis[n0 + t] = rsqrtf((float)hist[t] + 1.0f);
        cursor[t] = excl;
    }
    __syncthreads();
    for (int i = start + t; i < endp; i += 1024) {
        unsigned p = pairs[i];
        int pos = atomicAdd(&cursor[p >> 17], 1);
        int sv = (int)(p & 0x1FFFFu);
        if (big) col[start + pos] = sv;
        else lcol[pos] = sv;
    }
    __syncthreads();
    if (!big) {
        for (int i = t; i < cnt; i += 1024) col[start + i] = lcol[i];
    }
}

// ---------- compute ----------

__device__ inline unsigned pack_bf2(float a, float b) {
    __hip_bfloat162 t;
    t.x = __float2bfloat16(a);
    t.y = __float2bfloat16(b);
    unsigned u;
    __builtin_memcpy(&u, &t, 4);
    return u;
}

__device__ inline float bf_lo(unsigned u) {
    unsigned w = u << 16; float f; __builtin_memcpy(&f, &w, 4); return f;
}
__device__ inline float bf_hi(unsigned u) {
    unsigned w = u & 0xffff0000u; float f; __builtin_memcpy(&f, &w, 4); return f;
}

// uniform-base + 32-bit byte-offset dwordx4 load
__device__ inline uint4 ldx4(const unsigned* p, unsigned boff) {
    return *(const uint4*)((const char*)p + boff);
}

#define FMA32(x0, x1, x2, x3, wa, wb)                                        \
    a00 += (x0) * (wa).x; a01 += (x0) * (wa).y;                              \
    a02 += (x0) * (wa).z; a03 += (x0) * (wa).w;                              \
    a04 += (x0) * (wb).x; a05 += (x0) * (wb).y;                              \
    a06 += (x0) * (wb).z; a07 += (x0) * (wb).w;                              \
    a10 += (x1) * (wa).x; a11 += (x1) * (wa).y;                              \
    a12 += (x1) * (wa).z; a13 += (x1) * (wa).w;                              \
    a14 += (x1) * (wb).x; a15 += (x1) * (wb).y;                              \
    a16 += (x1) * (wb).z; a17 += (x1) * (wb).w;                              \
    a20 += (x2) * (wa).x; a21 += (x2) * (wa).y;                              \
    a22 += (x2) * (wa).z; a23 += (x2) * (wa).w;                              \
    a24 += (x2) * (wb).x; a25 += (x2) * (wb).y;                              \
    a26 += (x2) * (wb).z; a27 += (x2) * (wb).w;                              \
    a30 += (x3) * (wa).x; a31 += (x3) * (wa).y;                              \
    a32 += (x3) * (wa).z; a33 += (x3) * (wa).w;                              \
    a34 += (x3) * (wb).x; a35 += (x3) * (wb).y;                              \
    a36 += (x3) * (wb).z; a37 += (x3) * (wb).w;

// GEMM: 4 rows x 8 cols per thread (R16: was 2x8 — doubling rows halves the
// 8-way-redundant W LDS reads per output row AND halves total wave count;
// the kernel was LDS-read/instr-issue bound, not FLOP bound).  All named
// scalars (hipcc does not SROA private arrays).  unroll 2 to stay under the
// 128-VGPR cap of __launch_bounds__(256,4).
__global__ __launch_bounds__(256, 4)
void gemm64_scaled_kernel(const float* __restrict__ X, const float* __restrict__ W,
                          const float* __restrict__ dis,
                          __hip_bfloat16* __restrict__ Y, int n) {
    __shared__ float Ws[CH * CH];
    {
        float4* w4 = (float4*)Ws;
        const float4* g4 = (const float4*)W;
        for (int i = threadIdx.x; i < CH * CH / 4; i += 256) w4[i] = g4[i];
    }
    __syncthreads();
    int t = threadIdx.x;
    int cbase = (t & 7) * 8;
    int r0 = blockIdx.x * 128 + (t >> 3) * 4;
    if (r0 >= n) return;
    int rB = min(r0 + 1, n - 1);
    int rC = min(r0 + 2, n - 1);
    int rD = min(r0 + 3, n - 1);
    const float4* pA = (const float4*)(X + (size_t)r0 * CH);
    const float4* pB = (const float4*)(X + (size_t)rB * CH);
    const float4* pC = (const float4*)(X + (size_t)rC * CH);
    const float4* pD = (const float4*)(X + (size_t)rD * CH);

    float a00 = 0.f, a01 = 0.f, a02 = 0.f, a03 = 0.f;
    float a04 = 0.f, a05 = 0.f, a06 = 0.f, a07 = 0.f;
    float a10 = 0.f, a11 = 0.f, a12 = 0.f, a13 = 0.f;
    float a14 = 0.f, a15 = 0.f, a16 = 0.f, a17 = 0.f;
    float a20 = 0.f, a21 = 0.f, a22 = 0.f, a23 = 0.f;
    float a24 = 0.f, a25 = 0.f, a26 = 0.f, a27 = 0.f;
    float a30 = 0.f, a31 = 0.f, a32 = 0.f, a33 = 0.f;
    float a34 = 0.f, a35 = 0.f, a36 = 0.f, a37 = 0.f;

#pragma unroll 2
    for (int k4 = 0; k4 < CH / 4; ++k4) {
        float4 xa = pA[k4];
        float4 xb = pB[k4];
        float4 xc = pC[k4];
        float4 xd = pD[k4];
        const float* wr = &Ws[(k4 * 4) * CH + cbase];
        float4 wa, wb;
        wa = *(const float4*)(wr);
        wb = *(const float4*)(wr + 4);
        FMA32(xa.x, xb.x, xc.x, xd.x, wa, wb)
        wa = *(const float4*)(wr + CH);
        wb = *(const float4*)(wr + CH + 4);
        FMA32(xa.y, xb.y, xc.y, xd.y, wa, wb)
        wa = *(const float4*)(wr + 2 * CH);
        wb = *(const float4*)(wr + 2 * CH + 4);
        FMA32(xa.z, xb.z, xc.z, xd.z, wa, wb)
        wa = *(const float4*)(wr + 3 * CH);
        wb = *(const float4*)(wr + 3 * CH + 4);
        FMA32(xa.w, xb.w, xc.w, xd.w, wa, wb)
    }

    uint4 pk;
    float d0 = dis[r0];
    pk.x = pack_bf2(a00 * d0, a01 * d0);
    pk.y = pack_bf2(a02 * d0, a03 * d0);
    pk.z = pack_bf2(a04 * d0, a05 * d0);
    pk.w = pack_bf2(a06 * d0, a07 * d0);
    *(uint4*)(Y + (size_t)r0 * CH + cbase) = pk;
    if (r0 + 1 < n) {
        float d1 = dis[r0 + 1];
        pk.x = pack_bf2(a10 * d1, a11 * d1);
        pk.y = pack_bf2(a12 * d1, a13 * d1);
        pk.z = pack_bf2(a14 * d1, a15 * d1);
        pk.w = pack_bf2(a16 * d1, a17 * d1);
        *(uint4*)(Y + (size_t)(r0 + 1) * CH + cbase) = pk;
    }
    if (r0 + 2 < n) {
        float d2 = dis[r0 + 2];
        pk.x = pack_bf2(a20 * d2, a21 * d2);
        pk.y = pack_bf2(a22 * d2, a23 * d2);
        pk.z = pack_bf2(a24 * d2, a25 * d2);
        pk.w = pack_bf2(a26 * d2, a27 * d2);
        *(uint4*)(Y + (size_t)(r0 + 2) * CH + cbase) = pk;
    }
    if (r0 + 3 < n) {
        float d3 = dis[r0 + 3];
        pk.x = pack_bf2(a30 * d3, a31 * d3);
        pk.y = pack_bf2(a32 * d3, a33 * d3);
        pk.z = pack_bf2(a34 * d3, a35 * d3);
        pk.w = pack_bf2(a36 * d3, a37 * d3);
        *(uint4*)(Y + (size_t)(r0 + 3) * CH + cbase) = pk;
    }
}

// R16 gather: dwordx4 gather loads.  Row = 128B; 8 lanes (sub = lane&7) cover
// it with one uint4 each; grp = lane>>3 picks the edge -> 8 edges per
// wave-load instruction (was 2 with dword loads).  The kernel was bound by
// vector-memory INSTRUCTION rate (~19 cy/instr implied; HBM 29%, VALU ~50%,
// 0 bank conflicts), not bytes — same traffic, 4x fewer vmem instrs.
// acc mapping: word w of a row holds ch (2w, 2w+1); lane sub loads words
// 4sub..4sub+3 -> aL/aH q cover ch 8sub+2q / 8sub+2q+1.
#define ACC8(u)                                                               \
    aL0 += bf_lo((u).x); aH0 += bf_hi((u).x);                                 \
    aL1 += bf_lo((u).y); aH1 += bf_hi((u).y);                                 \
    aL2 += bf_lo((u).z); aH2 += bf_hi((u).z);                                 \
    aL3 += bf_lo((u).w); aH3 += bf_hi((u).w);

#define RED3(v)                                                               \
    v += __shfl_xor(v, 8, 64);                                                \
    v += __shfl_xor(v, 16, 64);                                               \
    v += __shfl_xor(v, 32, 64);

#define GATHER_X4_BODY(XWS)                                                   \
    int beg = rs[wid];                                                        \
    int end = (wid + 1 < n) ? rs[wid + 1] : E;                                \
    unsigned sub16 = (unsigned)(lane & 7) << 4;                               \
    int grp = lane >> 3;                                                      \
    float aL0 = 0.f, aH0 = 0.f, aL1 = 0.f, aH1 = 0.f;                         \
    float aL2 = 0.f, aH2 = 0.f, aL3 = 0.f, aH3 = 0.f;                         \
    uint4 uself = ldx4((XWS), ((unsigned)wid << 7) | sub16); /* hoisted */    \
    float dd = dis[wid];                                                      \
    for (int base = beg; base < end; base += 64) {                            \
        int cnt = min(64, end - base);                                        \
        int myCol = (base + lane < end) ? col[base + lane] : 0;               \
        int eb = 0;                                                           \
        for (; eb + 16 <= cnt; eb += 16) {                                    \
            unsigned o0 = ((unsigned)__shfl(myCol, eb + grp, 64) << 7) | sub16;     \
            unsigned o1 = ((unsigned)__shfl(myCol, eb + 8 + grp, 64) << 7) | sub16; \
            uint4 u0 = ldx4((XWS), o0);                                       \
            uint4 u1 = ldx4((XWS), o1);                                       \
            ACC8(u0)                                                          \
            ACC8(u1)                                                          \
        }                                                                     \
        for (; eb < cnt; eb += 8) {                                           \
            int ei = eb + grp;                                                \
            int ec = ei < cnt ? ei : cnt - 1;                                 \
            unsigned o = ((unsigned)__shfl(myCol, ec, 64) << 7) | sub16;      \
            uint4 u = ldx4((XWS), o);                                         \
            if (ei < cnt) { ACC8(u) }                                         \
        }                                                                     \
    }                                                                         \
    if (grp == 0) { ACC8(uself) }  /* self-loop once, summed by butterfly */  \
    RED3(aL0) RED3(aH0) RED3(aL1) RED3(aH1)                                   \
    RED3(aL2) RED3(aH2) RED3(aL3) RED3(aH3)                                   \
    int g01 = grp & 1;                                                        \
    float t0 = g01 ? aL2 : aL0;                                               \
    float t1 = g01 ? aH2 : aH0;                                               \
    float t2 = g01 ? aL3 : aL1;                                               \
    float t3 = g01 ? aH3 : aH1;

// Layer-1 gather: h[wid] fp32 row.  One node per wave (max TLP — R13's
// serial fusion was 2.3x slower).
__global__ __launch_bounds__(256)
void gather_pair_kernel(const unsigned* __restrict__ xws, const int* __restrict__ col,
                        const int* __restrict__ rs, const float* __restrict__ dis,
                        const float* __restrict__ b1, float* __restrict__ h,
                        int n, int E) {
    int wid = blockIdx.x * 4 + (threadIdx.x >> 6);
    int lane = threadIdx.x & 63;
    if (wid >= n) return;

    GATHER_X4_BODY(xws)

    float4 bb = ((const float4*)b1)[((lane & 7) << 1) | g01];
    float4 o;
    o.x = fmaxf(dd * t0 + bb.x, 0.f);
    o.y = fmaxf(dd * t1 + bb.y, 0.f);
    o.z = fmaxf(dd * t2 + bb.z, 0.f);
    o.w = fmaxf(dd * t3 + bb.w, 0.f);
    if (grp < 2)
        ((float4*)h)[(size_t)wid * 16 + ((lane & 7) << 1) + g01] = o;
}

// Layer-2 gather + relu + LN partials accumulated straight into so[2..3]
// (R16: 25k block-partial float atomics over ~40us — no contention; kills
// the single-block reduce_final kernel).
__global__ __launch_bounds__(256)
void gather_stats_kernel(const unsigned* __restrict__ xws, const int* __restrict__ col,
                         const int* __restrict__ rs, const float* __restrict__ dis,
                         const float* __restrict__ b2, float* __restrict__ out,
                         int n, int E, float* __restrict__ so) {
    int wid = blockIdx.x * 4 + (threadIdx.x >> 6);
    int lane = threadIdx.x & 63;
    float s = 0.f, sq = 0.f;
    if (wid < n) {
        GATHER_X4_BODY(xws)
        float4 bb = ((const float4*)b2)[((lane & 7) << 1) | g01];
        float4 o;
        o.x = fmaxf(dd * t0 + bb.x, 0.f);
        o.y = fmaxf(dd * t1 + bb.y, 0.f);
        o.z = fmaxf(dd * t2 + bb.z, 0.f);
        o.w = fmaxf(dd * t3 + bb.w, 0.f);
        if (grp < 2) {
            ((float4*)out)[(size_t)wid * 16 + ((lane & 7) << 1) + g01] = o;
            s = o.x + o.y + o.z + o.w;
            sq = o.x * o.x + o.y * o.y + o.z * o.z + o.w * o.w;
        }
    }
#pragma unroll
    for (int off = 32; off > 0; off >>= 1) {
        s += __shfl_down(s, off, 64);
        sq += __shfl_down(sq, off, 64);
    }
    __shared__ float ls[4], lq[4];
    int w = threadIdx.x >> 6;
    if ((threadIdx.x & 63) == 0) { ls[w] = s; lq[w] = sq; }
    __syncthreads();
    if (threadIdx.x == 0) {
        atomicAdd(&so[2], ls[0] + ls[1] + ls[2] + ls[3]);
        atomicAdd(&so[3], lq[0] + lq[1] + lq[2] + lq[3]);
    }
}

// LN apply; scale/offset derived per-thread from the two accumulated sums
// (uniform loads -> s_load; ~8 VALU/thread).
__global__ void norm_kernel(float* __restrict__ x, int n4, const float* __restrict__ so,
                            float inv_n, const float* __restrict__ lnw,
                            const float* __restrict__ lnb) {
    int i = blockIdx.x * blockDim.x + threadIdx.x;
    if (i >= n4) return;
    float mean = so[2] * inv_n;
    float var = so[3] * inv_n - mean * mean;
    float scale = rsqrtf(var + 1e-5f) * lnw[0];
    float off = lnb[0] - mean * scale;
    float4* x4 = (float4*)x;
    float4 v = x4[i];
    v.x = v.x * scale + off;
    v.y = v.y * scale + off;
    v.z = v.z * scale + off;
    v.w = v.w * scale + off;
    x4[i] = v;
}

extern "C" void kernel_launch(void* const* d_in, const int* in_sizes, int n_in,
                              void* d_out, int out_size, void* d_ws, size_t ws_size,
                              hipStream_t stream) {
    const float* X   = (const float*)d_in[0];
    const int*   edg = (const int*)d_in[1];   // [2,E]: src row then dst row
    const float* W1  = (const float*)d_in[2];
    const float* b1  = (const float*)d_in[3];
    const float* W2  = (const float*)d_in[4];
    const float* b2  = (const float*)d_in[5];
    const float* lnw = (const float*)d_in[6];
    const float* lnb = (const float*)d_in[7];
    float* out = (float*)d_out;

    const int N  = in_sizes[0] / CH;   // 100000
    const int E  = in_sizes[1] / 2;    // 1600000
    const int NC = N * CH;             // 6.4M
    const int nNodeBlk = (N + 3) / 4;  // 25000 (4 nodes / block)
    const int nb = (N + 511) >> BSH;   // 196 buckets
    const int nblkE = (E + CHUNK - 1) / CHUNK;  // 98 edge-chunk blocks

    const int* srcp = edg;
    const int* dstp = edg + E;

    // workspace layout (4B units).  pairs (E unsigned) dead after bucket_csr;
    // h (NC floats) overlays it.
    int*   col   = (int*)d_ws;                          // E
    int*   rs    = col + E;                             // N
    float* dis   = (float*)(rs + N);                    // N
    __hip_bfloat16* xws1 = (__hip_bfloat16*)(dis + N);  // NC bf16
    __hip_bfloat16* xws2 = xws1 + NC;                   // NC bf16
    float* h     = (float*)(xws2 + NC);                 // NC floats
    unsigned* pairs = (unsigned*)h;                     // E u32 (dead before h live)
    int*   bHist = (int*)(h + NC);                      // nblkE*nb
    int*   bStart= bHist + nblkE * nb;                  // nb+1
    float* so    = (float*)(bStart + nb + 1);           // 4 {scale, offset, sum, sqsum}

    const int B = 256;
    const int nGemmBlk = (N + 127) / 128;               // 782 (4 rows/thread)

    // ---- CSR build (no global atomics, no memset) ----
    coarse_hist_kernel<<<nblkE, 1024, 0, stream>>>(dstp, bHist, E, nb);
    scan_hist_kernel<<<1, 256, 0, stream>>>(bHist, bStart, nblkE, nb, so);
    scatter_pairs_kernel<<<nblkE, 1024, 0, stream>>>(srcp, dstp, bHist, pairs, E, nb);
    bucket_csr_kernel<<<nb, 1024, 0, stream>>>(pairs, bStart, col, rs, dis, N, nb);
    // rs = row_start; row i spans [rs[i], rs[i+1]), last row ends at E

    // ---- layer 1 ----
    gemm64_scaled_kernel<<<nGemmBlk, B, 0, stream>>>(X, W1, dis, xws1, N);
    gather_pair_kernel<<<nNodeBlk, B, 0, stream>>>((const unsigned*)xws1, col, rs, dis,
                                                   b1, h, N, E);

    // ---- layer 2 ----
    gemm64_scaled_kernel<<<nGemmBlk, B, 0, stream>>>(h, W2, dis, xws2, N);
    gather_stats_kernel<<<nNodeBlk, B, 0, stream>>>((const unsigned*)xws2, col, rs, dis,
                                                    b2, out, N, E, so);

    // ---- graph layernorm (scale derived in norm itself) ----
    norm_kernel<<<(NC / 4 + B - 1) / B, B, 0, stream>>>(out, NC / 4, so, 1.0f / NC, lnw, lnb);
}